// Round 9
// baseline (2120.111 us; speedup 1.0000x reference)
//
#include <hip/hip_runtime.h>

#define BB 8
#define LL 2048
#define DD 512
#define QQ 8
#define KK 2048
#define MM (BB*LL)      // 16384 points

#define NTILES 16       // 16 col-tiles of 128

typedef __attribute__((ext_vector_type(8))) short short8;
typedef __attribute__((ext_vector_type(4))) float f32x4;

#define GLDS(src, dst) __builtin_amdgcn_global_load_lds( \
    (const __attribute__((address_space(1))) void*)(src), \
    (__attribute__((address_space(3))) void*)(dst), 16, 0, 0)

#define BARX()  asm volatile("s_barrier" ::: "memory")
#define WAIT0() asm volatile("s_waitcnt vmcnt(0)" ::: "memory")

__device__ __forceinline__ ushort f2bf(float f) {
    uint u = __float_as_uint(f);
    u += 0x7FFFu + ((u >> 16) & 1u);
    return (ushort)(u >> 16);
}

// ---------------- cb2: fp32 squared norms ----------------
__global__ __launch_bounds__(256) void cb2_kernel(const float* __restrict__ cb,
                                                  float* __restrict__ cb2) {
    int row  = blockIdx.x * 4 + (threadIdx.x >> 6);
    int lane = threadIdx.x & 63;
    const float* r = cb + (size_t)row * DD + lane * 8;
    float4 a = *(const float4*)r;
    float4 b = *(const float4*)(r + 4);
    float s = a.x*a.x + a.y*a.y + a.z*a.z + a.w*a.w
            + b.x*b.x + b.y*b.y + b.z*b.z + b.w*b.w;
    #pragma unroll
    for (int off = 32; off >= 1; off >>= 1) s += __shfl_xor(s, off);
    if (lane == 0) cb2[row] = s;
}

// ---------------- B prep: bh2[col*64 + j] = bf16 of cbq[col][j*8..j*8+8) ----------------
__global__ __launch_bounds__(256) void bprep_kernel(const float* __restrict__ cbq,
                                                    short8* __restrict__ bh2) {
    const int wid  = threadIdx.x >> 6;
    const int lane = threadIdx.x & 63;
    const int col  = blockIdx.x * 4 + wid;
    const float* src = cbq + (size_t)col * DD + lane * 8;
    float4 v0 = *(const float4*)src;
    float4 v1 = *(const float4*)(src + 4);
    short8 h;
    h[0] = (short)f2bf(v0.x); h[1] = (short)f2bf(v0.y);
    h[2] = (short)f2bf(v0.z); h[3] = (short)f2bf(v0.w);
    h[4] = (short)f2bf(v1.x); h[5] = (short)f2bf(v1.y);
    h[6] = (short)f2bf(v1.z); h[7] = (short)f2bf(v1.w);
    bh2[(size_t)col * 64 + lane] = h;
}

// ---------------- level-0 A prep: resid <- x, ah <- bf16(x) [row][lane]; zero cnt ----
__global__ __launch_bounds__(256) void aprep0_kernel(const float* __restrict__ x,
                                                     float* __restrict__ resid,
                                                     short8* __restrict__ ah,
                                                     int* __restrict__ cnt) {
    if (blockIdx.x == 0 && threadIdx.x < 64) cnt[threadIdx.x] = 0;
    const int wid  = threadIdx.x >> 6;
    const int lane = threadIdx.x & 63;
    const int row  = blockIdx.x * 4 + wid;
    const float* src = x + (size_t)row * DD + lane * 8;
    float4 v0 = *(const float4*)src;
    float4 v1 = *(const float4*)(src + 4);
    float* dst = resid + (size_t)row * DD + lane * 8;
    *(float4*)dst       = v0;
    *(float4*)(dst + 4) = v1;
    short8 h;
    h[0] = (short)f2bf(v0.x); h[1] = (short)f2bf(v0.y);
    h[2] = (short)f2bf(v0.z); h[3] = (short)f2bf(v0.w);
    h[4] = (short)f2bf(v1.x); h[5] = (short)f2bf(v1.y);
    h[6] = (short)f2bf(v1.z); h[7] = (short)f2bf(v1.w);
    ah[(size_t)row * 64 + lane] = h;
}

// ---------------- 256x256 BK=64 bf16 GEMM + masks + FUSED exact refine ----------------
// K-loop and mask epilogue identical to r8 (proven, equal-best). New: after mask
// writes, blocks sharing row-panel mt rendezvous via device-scope atomic counter;
// the 8th arrival refines its 256 rows in-kernel (32 groups x 16 lanes, 1 row/group,
// resid slice in registers). Deletes the standalone crru kernel + 8 launches.
__global__ __launch_bounds__(512, 2) void gemm_argmin_kernel(
    const short8* __restrict__ ah,
    const short8* __restrict__ bh2,
    const float*  __restrict__ cb2q,
    const float*  __restrict__ cbq,
    const float*  __restrict__ xin,
    float*        __restrict__ blockv1,    // [NTILES][MM]
    uint4*        __restrict__ blockmask,  // [NTILES][MM]
    float*        __restrict__ resid,
    float*        __restrict__ idx_out,
    short8*       __restrict__ ahout,
    int*          __restrict__ cnt,        // [64] per-mt rendezvous
    int q, float W)
{
    __shared__ char smemc[131072];   // [2 buf][A 32KB | B 32KB]

    const int id  = blockIdx.x;
    const int xcd = id & 7;
    const int s   = id >> 3;             // 0..63
    const int nt  = s & 7;               // 0..7 (256-col tiles)
    const int mt  = xcd * 8 + (s >> 3);  // 0..63 (256-row tiles), A reuse per XCD

    const int tid  = threadIdx.x;
    const int wid  = tid >> 6;
    const int lane = tid & 63;
    const int wr   = wid >> 2;           // rows [wr*128, +128)
    const int wcn  = wid & 3;            // cols [wcn*64, +64)
    const int l15  = lane & 15, l4 = lane >> 4;

    f32x4 acc[4][8];
    #pragma unroll
    for (int n = 0; n < 4; n++)
        #pragma unroll
        for (int m = 0; m < 8; m++) acc[n][m] = (f32x4){0.f, 0.f, 0.f, 0.f};

    const char* aSrc = (const char*)ah  + ((size_t)mt << 18);   // 256 rows x 1 KB
    const char* bSrc = (const char*)bh2 + ((size_t)nt << 18);

    #define STAGEQ(tt, bufn, p) do { \
        int g_ = (p) * 512 + tid; \
        int rL_ = g_ >> 3, st_ = g_ & 7; \
        int k_ = st_ ^ (rL_ & 7); \
        char* db_ = smemc + (bufn) * 65536 + ((p) * 512 + wid * 64) * 16; \
        GLDS(aSrc + (size_t)rL_ * 1024 + (tt) * 128 + k_ * 16, db_); \
        GLDS(bSrc + (size_t)rL_ * 1024 + (tt) * 128 + k_ * 16, db_ + 32768); \
    } while (0)

    short8 af[4][2], bf[4][2];

    #define LDA(mh) do { \
        _Pragma("unroll") for (int mm = 0; mm < 4; mm++) \
        _Pragma("unroll") for (int ks = 0; ks < 2; ks++) { \
            int rL_ = wr * 128 + ((mh) * 4 + mm) * 16 + l15; \
            int c_ = ks * 4 + l4; \
            af[mm][ks] = *(const short8*)(smemc + ab + rL_ * 128 + ((c_ ^ (rL_ & 7)) << 4)); \
        } } while (0)

    #define LDBALL() do { \
        _Pragma("unroll") for (int nn = 0; nn < 4; nn++) \
        _Pragma("unroll") for (int ks = 0; ks < 2; ks++) { \
            int cL_ = wcn * 64 + nn * 16 + l15; \
            int c_ = ks * 4 + l4; \
            bf[nn][ks] = *(const short8*)(smemc + ab + 32768 + cL_ * 128 + ((c_ ^ (cL_ & 7)) << 4)); \
        } } while (0)

    #define PH(mh) do { \
        __builtin_amdgcn_s_setprio(1); \
        _Pragma("unroll") for (int ks = 0; ks < 2; ks++) \
        _Pragma("unroll") for (int nn = 0; nn < 4; nn++) \
        _Pragma("unroll") for (int mm = 0; mm < 4; mm++) \
            acc[nn][(mh)*4+mm] = __builtin_amdgcn_mfma_f32_16x16x32_bf16( \
                bf[nn][ks], af[mm][ks], acc[nn][(mh)*4+mm], 0, 0, 0); \
        __builtin_amdgcn_s_setprio(0); \
    } while (0)

    STAGEQ(0, 0, 0); STAGEQ(0, 0, 1); STAGEQ(0, 0, 2); STAGEQ(0, 0, 3);
    WAIT0();
    BARX();

    for (int t = 0; t < 8; t++) {
        const uint ab = (uint)(t & 1) * 65536u;
        const int nbuf = (t & 1) ^ 1;
        if (t < 7) { STAGEQ(t + 1, nbuf, 0); STAGEQ(t + 1, nbuf, 1);
                     STAGEQ(t + 1, nbuf, 2); STAGEQ(t + 1, nbuf, 3); }
        LDBALL();
        LDA(0);
        PH(0);
        LDA(1);
        PH(1);
        if (t < 7) WAIT0();
        BARX();
    }

    // ---- mask epilogue (r8-verbatim) ----
    float* halfmin = (float*)smemc;             // [256][4 wcn]  4 KB
    uint2* maskS   = (uint2*)(smemc + 4096);    // [256][4 wcn]  8 KB

    f32x4 c2v[4];
    #pragma unroll
    for (int n = 0; n < 4; n++)
        c2v[n] = *(const f32x4*)&cb2q[nt * 256 + wcn * 64 + n * 16 + (l4 << 2)];

    #pragma unroll
    for (int m = 0; m < 8; m++) {
        float v = 3.4e38f;
        #pragma unroll
        for (int n = 0; n < 4; n++)
            #pragma unroll
            for (int r = 0; r < 4; r++)
                v = fminf(v, fmaf(-2.f, acc[n][m][r], c2v[n][r]));
        v = fminf(v, __shfl_xor(v, 16));
        v = fminf(v, __shfl_xor(v, 32));
        if (l4 == 0) halfmin[(wr * 128 + m * 16 + l15) * 4 + wcn] = v;
    }
    __syncthreads();

    #pragma unroll
    for (int m = 0; m < 8; m++) {
        int rL = wr * 128 + m * 16 + l15;
        int pb = wcn & 2;
        float vt = fminf(halfmin[rL * 4 + pb], halfmin[rL * 4 + pb + 1]);
        float thrm = vt + W;
        uint blo = 0, bhi = 0;
        #pragma unroll
        for (int n = 0; n < 4; n++)
            #pragma unroll
            for (int r = 0; r < 4; r++) {
                float d = fmaf(-2.f, acc[n][m][r], c2v[n][r]);
                int bit = n * 16 + (l4 << 2) + r;
                if (d < thrm) { if (bit < 32) blo |= 1u << bit; else bhi |= 1u << (bit - 32); }
            }
        blo |= __shfl_xor(blo, 16); bhi |= __shfl_xor(bhi, 16);
        blo |= __shfl_xor(blo, 32); bhi |= __shfl_xor(bhi, 32);
        if (l4 == 0) maskS[rL * 4 + wcn] = make_uint2(blo, bhi);
    }
    __syncthreads();

    {
        int T = tid >> 8, rL = tid & 255;
        float vt = fminf(halfmin[rL * 4 + T * 2], halfmin[rL * 4 + T * 2 + 1]);
        uint2 lo = maskS[rL * 4 + T * 2], hi = maskS[rL * 4 + T * 2 + 1];
        size_t o = (size_t)(nt * 2 + T) * MM + mt * 256 + rL;
        blockv1[o] = vt;
        blockmask[o] = make_uint4(lo.x, lo.y, hi.x, hi.y);
    }
    #undef STAGEQ
    #undef LDA
    #undef LDBALL
    #undef PH

    // ---- rendezvous: last of the 8 nt-siblings for this mt runs the refine ----
    __threadfence();                 // release: mask writes device-visible
    __syncthreads();                 // orders tid0's atomic after all threads' fences
    int* flag = (int*)smemc;
    if (tid == 0) {
        int old = atomicAdd(&cnt[mt], 1);    // device scope by default
        flag[0] = (old == 7);
    }
    __syncthreads();
    if (!flag[0]) return;
    __threadfence();                 // acquire before reading siblings' masks
    if (tid == 0) cnt[mt] = 0;       // reset for next level (kernel-boundary vis.)

    // ---- fused exact refine: 32 groups x 16 lanes, one row per group, 8 rows each
    const int gi    = tid >> 4;      // 0..31
    const int gl    = tid & 15;
    const int gbase = lane & 48;     // group base within wave

    for (int rr = 0; rr < 8; rr++) {
        const int row = mt * 256 + gi * 8 + rr;

        // lane gl owns resid floats [gl*32, +32) of this row
        const float* rrow = resid + (size_t)row * DD + gl * 32;
        float4 rg[8];
        #pragma unroll
        for (int j = 0; j < 8; j++) rg[j] = *(const float4*)(rrow + j * 4);

        size_t o = (size_t)gl * MM + row;    // lane gl loads tile gl
        float v1 = blockv1[o];
        uint4 mk = blockmask[o];
        float g1 = v1;
        #pragma unroll
        for (int off = 8; off >= 1; off >>= 1) g1 = fminf(g1, __shfl_xor(g1, off));
        const float thr = g1 + W;
        uint actg = (uint)((__ballot(v1 < thr) >> gbase) & 0xFFFFull);

        float be = 3.4e38f; int bk = 0x7FFFFFFF;
        while (actg) {
            int tile = __ffs(actg) - 1; actg &= actg - 1;
            int sl = gbase + tile;
            uint m0 = __shfl((int)mk.x, sl), m1 = __shfl((int)mk.y, sl);
            uint m2 = __shfl((int)mk.z, sl), m3 = __shfl((int)mk.w, sl);
            unsigned long long lo = ((unsigned long long)m1 << 32) | m0;
            unsigned long long hi = ((unsigned long long)m3 << 32) | m2;
            int base = tile * 128;
            while (lo | hi) {
                int c;
                if (lo) { int b = __ffsll(lo) - 1; lo &= lo - 1; c = base + b; }
                else    { int b = __ffsll(hi) - 1; hi &= hi - 1; c = base + 64 + b; }
                const float* cp = cbq + (size_t)c * DD + gl * 32;
                float d0 = 0.f, d1 = 0.f;
                #pragma unroll
                for (int j = 0; j < 8; j += 2) {
                    float4 ca = *(const float4*)(cp + j * 4);
                    float4 cb_ = *(const float4*)(cp + j * 4 + 4);
                    d0 = fmaf(rg[j].x, ca.x, d0);   d0 = fmaf(rg[j].y, ca.y, d0);
                    d0 = fmaf(rg[j].z, ca.z, d0);   d0 = fmaf(rg[j].w, ca.w, d0);
                    d1 = fmaf(rg[j+1].x, cb_.x, d1); d1 = fmaf(rg[j+1].y, cb_.y, d1);
                    d1 = fmaf(rg[j+1].z, cb_.z, d1); d1 = fmaf(rg[j+1].w, cb_.w, d1);
                }
                float d = d0 + d1;
                #pragma unroll
                for (int off = 8; off >= 1; off >>= 1) d += __shfl_xor(d, off);
                float e = fmaf(-2.f, d, cb2q[c]);
                if (e < be || (e == be && c < bk)) { be = e; bk = c; }
            }
        }
        const int winner = bk;   // uniform within group (d, c group-uniform)

        if (gl == 0) {
            int b = row >> 11, l = row & (LL - 1);
            idx_out[((size_t)b * QQ + q) * LL + l] = (float)winner;
        }

        const float* cw = cbq + (size_t)winner * DD + gl * 32;
        float* wrp = resid + (size_t)row * DD + gl * 32;
        if (q < QQ - 1) {
            #pragma unroll
            for (int j = 0; j < 4; j++) {
                float4 ca = *(const float4*)(cw + j * 8);
                float4 cb_ = *(const float4*)(cw + j * 8 + 4);
                float4 na = make_float4(rg[j*2].x - ca.x, rg[j*2].y - ca.y,
                                        rg[j*2].z - ca.z, rg[j*2].w - ca.w);
                float4 nb = make_float4(rg[j*2+1].x - cb_.x, rg[j*2+1].y - cb_.y,
                                        rg[j*2+1].z - cb_.z, rg[j*2+1].w - cb_.w);
                *(float4*)(wrp + j * 8)     = na;
                *(float4*)(wrp + j * 8 + 4) = nb;
                short8 h;
                h[0] = (short)f2bf(na.x); h[1] = (short)f2bf(na.y);
                h[2] = (short)f2bf(na.z); h[3] = (short)f2bf(na.w);
                h[4] = (short)f2bf(nb.x); h[5] = (short)f2bf(nb.y);
                h[6] = (short)f2bf(nb.z); h[7] = (short)f2bf(nb.w);
                ahout[(size_t)row * 64 + gl * 4 + j] = h;
            }
        } else {
            // final level: quantized = x - (r - c) = x - r + c
            const float* xw = xin + (size_t)row * DD + gl * 32;
            #pragma unroll
            for (int j = 0; j < 8; j++) {
                float4 cv = *(const float4*)(cw + j * 4);
                float4 xv = *(const float4*)(xw + j * 4);
                *(float4*)(wrp + j * 4) =
                    make_float4(xv.x - rg[j].x + cv.x, xv.y - rg[j].y + cv.y,
                                xv.z - rg[j].z + cv.z, xv.w - rg[j].w + cv.w);
            }
        }
    }
}

extern "C" void kernel_launch(void* const* d_in, const int* in_sizes, int n_in,
                              void* d_out, int out_size, void* d_ws, size_t ws_size,
                              hipStream_t stream) {
    (void)in_sizes; (void)n_in; (void)out_size; (void)ws_size;
    const float* x  = (const float*)d_in[0];
    const float* cb = (const float*)d_in[1];
    float* out = (float*)d_out;

    float* idx_out = out;                           // BB*QQ*LL floats
    float* resid   = out + (size_t)BB * QQ * LL;    // doubles as quantized output

    char* w = (char*)d_ws;
    float*  cb2       = (float*)(w);                 // 64 KB
    float*  blockv1   = (float*)(w + 0x10000);       // 1 MB  -> ends 0x110000
    uint4*  blockmask = (uint4*)(w + 0x110000);      // 4 MB  -> ends 0x510000
    short8* ah        = (short8*)(w + 0x510000);     // 16 MB -> ends 0x1510000
    short8* bh2       = (short8*)(w + 0x1510000);    // 2 MB  -> ends 0x1710000
    int*    cnt       = (int*)(w + 0x1710000);       // 256 B (~24 MB total)

    cb2_kernel<<<QQ * KK / 4, 256, 0, stream>>>(cb, cb2);
    aprep0_kernel<<<MM / 4, 256, 0, stream>>>(x, resid, ah, cnt);

    for (int q = 0; q < QQ; q++) {
        const float* cbq = cb + (size_t)q * KK * DD;
        const float* c2q = cb2 + (size_t)q * KK;
        const float W = 2.0f + 0.3f * q;   // proven coverage window (R7-R9)

        bprep_kernel<<<KK / 4, 256, 0, stream>>>(cbq, bh2);

        gemm_argmin_kernel<<<512, 512, 0, stream>>>(ah, bh2, c2q, cbq, x,
                                                    blockv1, blockmask, resid,
                                                    idx_out, ah, cnt, q, W);
    }
}

// Round 10
// 648.619 us; speedup vs baseline: 3.2687x; 3.2687x over previous
//
#include <hip/hip_runtime.h>

#define BB 8
#define LL 2048
#define DD 512
#define QQ 8
#define KK 2048
#define MM (BB*LL)      // 16384 points

#define NTILES 16       // 16 col-tiles of 128

typedef __attribute__((ext_vector_type(8))) short short8;
typedef __attribute__((ext_vector_type(4))) float f32x4;

#define GLDS(src, dst) __builtin_amdgcn_global_load_lds( \
    (const __attribute__((address_space(1))) void*)(src), \
    (__attribute__((address_space(3))) void*)(dst), 16, 0, 0)

#define BARX()  asm volatile("s_barrier" ::: "memory")
#define WAIT0() asm volatile("s_waitcnt vmcnt(0)" ::: "memory")

__device__ __forceinline__ ushort f2bf(float f) {
    uint u = __float_as_uint(f);
    u += 0x7FFFu + ((u >> 16) & 1u);
    return (ushort)(u >> 16);
}

// ---------------- cb2: fp32 squared norms ----------------
__global__ __launch_bounds__(256) void cb2_kernel(const float* __restrict__ cb,
                                                  float* __restrict__ cb2) {
    int row  = blockIdx.x * 4 + (threadIdx.x >> 6);
    int lane = threadIdx.x & 63;
    const float* r = cb + (size_t)row * DD + lane * 8;
    float4 a = *(const float4*)r;
    float4 b = *(const float4*)(r + 4);
    float s = a.x*a.x + a.y*a.y + a.z*a.z + a.w*a.w
            + b.x*b.x + b.y*b.y + b.z*b.z + b.w*b.w;
    #pragma unroll
    for (int off = 32; off >= 1; off >>= 1) s += __shfl_xor(s, off);
    if (lane == 0) cb2[row] = s;
}

// ---------------- B prep ALL LEVELS once: bh2all[(q*KK+col)*64 + j] ----------------
// Codebooks are input-static -> hoisted out of the level loop (removes 8 dispatches
// from the serial chain crru(q) -> gemm(q+1)).
__global__ __launch_bounds__(256) void bprep_kernel(const float* __restrict__ cb,
                                                    short8* __restrict__ bh2all) {
    const int wid  = threadIdx.x >> 6;
    const int lane = threadIdx.x & 63;
    const int col  = blockIdx.x * 4 + wid;      // 0 .. QQ*KK-1
    const float* src = cb + (size_t)col * DD + lane * 8;
    float4 v0 = *(const float4*)src;
    float4 v1 = *(const float4*)(src + 4);
    short8 h;
    h[0] = (short)f2bf(v0.x); h[1] = (short)f2bf(v0.y);
    h[2] = (short)f2bf(v0.z); h[3] = (short)f2bf(v0.w);
    h[4] = (short)f2bf(v1.x); h[5] = (short)f2bf(v1.y);
    h[6] = (short)f2bf(v1.z); h[7] = (short)f2bf(v1.w);
    bh2all[(size_t)col * 64 + lane] = h;
}

// ---------------- level-0 A prep: resid <- x, ah <- bf16(x) [row][lane] ----------------
__global__ __launch_bounds__(256) void aprep0_kernel(const float* __restrict__ x,
                                                     float* __restrict__ resid,
                                                     short8* __restrict__ ah) {
    const int wid  = threadIdx.x >> 6;
    const int lane = threadIdx.x & 63;
    const int row  = blockIdx.x * 4 + wid;
    const float* src = x + (size_t)row * DD + lane * 8;
    float4 v0 = *(const float4*)src;
    float4 v1 = *(const float4*)(src + 4);
    float* dst = resid + (size_t)row * DD + lane * 8;
    *(float4*)dst       = v0;
    *(float4*)(dst + 4) = v1;
    short8 h;
    h[0] = (short)f2bf(v0.x); h[1] = (short)f2bf(v0.y);
    h[2] = (short)f2bf(v0.z); h[3] = (short)f2bf(v0.w);
    h[4] = (short)f2bf(v1.x); h[5] = (short)f2bf(v1.y);
    h[6] = (short)f2bf(v1.z); h[7] = (short)f2bf(v1.w);
    ah[(size_t)row * 64 + lane] = h;
}

// ---------------- 256x256 BK=64 bf16 GEMM + masks, TWO mt panels per block ----------------
// r8-proven K-loop (1 barrier-pair per tile, compiler-scheduled body, XOR-swizzled
// GLDS staging). New: 256 blocks (1/CU, single round); each block runs 16 virtual
// K-tiles = two mt panels over the same nt; mid-kernel mask epilogue at vt=7
// (scratch ABOVE the staging buffers, LDS 144KB). Halves pipeline fill/drain and
// removes the 2-round grid tail. K-accumulation order per output unchanged ->
// masks bit-identical to r8.
__global__ __launch_bounds__(512, 2) void gemm_argmin_kernel(
    const short8* __restrict__ ah,
    const short8* __restrict__ bh2q,
    const float*  __restrict__ cb2q,
    float*        __restrict__ blockv1,    // [NTILES][MM]
    uint4*        __restrict__ blockmask,  // [NTILES][MM]
    float W)
{
    __shared__ char smemc[147456];   // [2 x 64KB staging][12KB epilogue scratch]

    const int id  = blockIdx.x;          // 0..255
    const int xcd = id & 7;
    const int s   = id >> 3;             // 0..31
    const int nt  = s & 7;               // 0..7 (256-col tiles)
    const int mt0 = xcd * 8 + (s >> 3) * 2;   // first of the mt pair

    const int tid  = threadIdx.x;
    const int wid  = tid >> 6;
    const int lane = tid & 63;
    const int wr   = wid >> 2;           // rows [wr*128, +128)
    const int wcn  = wid & 3;            // cols [wcn*64, +64)
    const int l15  = lane & 15, l4 = lane >> 4;

    f32x4 acc[4][8];
    #pragma unroll
    for (int n = 0; n < 4; n++)
        #pragma unroll
        for (int m = 0; m < 8; m++) acc[n][m] = (f32x4){0.f, 0.f, 0.f, 0.f};

    const char* aS0  = (const char*)ah + ((size_t)mt0 << 18);        // 256 rows x 1KB
    const char* aS1  = aS0 + (1 << 18);
    const char* bSrc = (const char*)bh2q + ((size_t)nt << 18);

    #define STAGEQ(abase, tt, bufn, p) do { \
        int g_ = (p) * 512 + tid; \
        int rL_ = g_ >> 3, st_ = g_ & 7; \
        int k_ = st_ ^ (rL_ & 7); \
        char* db_ = smemc + (bufn) * 65536 + ((p) * 512 + wid * 64) * 16; \
        GLDS((abase) + (size_t)rL_ * 1024 + (tt) * 128 + k_ * 16, db_); \
        GLDS(bSrc + (size_t)rL_ * 1024 + (tt) * 128 + k_ * 16, db_ + 32768); \
    } while (0)
    #define STAGE4(abase, tt, bufn) do { \
        STAGEQ(abase, tt, bufn, 0); STAGEQ(abase, tt, bufn, 1); \
        STAGEQ(abase, tt, bufn, 2); STAGEQ(abase, tt, bufn, 3); \
    } while (0)

    short8 af[4][2], bf[4][2];

    #define LDA(mh) do { \
        _Pragma("unroll") for (int mm = 0; mm < 4; mm++) \
        _Pragma("unroll") for (int ks = 0; ks < 2; ks++) { \
            int rL_ = wr * 128 + ((mh) * 4 + mm) * 16 + l15; \
            int c_ = ks * 4 + l4; \
            af[mm][ks] = *(const short8*)(smemc + ab + rL_ * 128 + ((c_ ^ (rL_ & 7)) << 4)); \
        } } while (0)

    #define LDBALL() do { \
        _Pragma("unroll") for (int nn = 0; nn < 4; nn++) \
        _Pragma("unroll") for (int ks = 0; ks < 2; ks++) { \
            int cL_ = wcn * 64 + nn * 16 + l15; \
            int c_ = ks * 4 + l4; \
            bf[nn][ks] = *(const short8*)(smemc + ab + 32768 + cL_ * 128 + ((c_ ^ (cL_ & 7)) << 4)); \
        } } while (0)

    #define PH(mh) do { \
        __builtin_amdgcn_s_setprio(1); \
        _Pragma("unroll") for (int ks = 0; ks < 2; ks++) \
        _Pragma("unroll") for (int nn = 0; nn < 4; nn++) \
        _Pragma("unroll") for (int mm = 0; mm < 4; mm++) \
            acc[nn][(mh)*4+mm] = __builtin_amdgcn_mfma_f32_16x16x32_bf16( \
                bf[nn][ks], af[mm][ks], acc[nn][(mh)*4+mm], 0, 0, 0); \
        __builtin_amdgcn_s_setprio(0); \
    } while (0)

    // mask epilogue for panel mtx (r8-verbatim, scratch above staging buffers)
    float* halfmin = (float*)(smemc + 131072);           // [256][4]  4KB
    uint2* maskS   = (uint2*)(smemc + 131072 + 4096);    // [256][4]  8KB

    f32x4 c2v[4];
    #pragma unroll
    for (int n = 0; n < 4; n++)
        c2v[n] = *(const f32x4*)&cb2q[nt * 256 + wcn * 64 + n * 16 + (l4 << 2)];

    #define EPI(mtx) do { \
        _Pragma("unroll") for (int m = 0; m < 8; m++) { \
            float v = 3.4e38f; \
            _Pragma("unroll") for (int n = 0; n < 4; n++) \
            _Pragma("unroll") for (int r = 0; r < 4; r++) \
                v = fminf(v, fmaf(-2.f, acc[n][m][r], c2v[n][r])); \
            v = fminf(v, __shfl_xor(v, 16)); \
            v = fminf(v, __shfl_xor(v, 32)); \
            if (l4 == 0) halfmin[(wr * 128 + m * 16 + l15) * 4 + wcn] = v; \
        } \
        __syncthreads(); \
        _Pragma("unroll") for (int m = 0; m < 8; m++) { \
            int rL = wr * 128 + m * 16 + l15; \
            int pb = wcn & 2; \
            float vt = fminf(halfmin[rL * 4 + pb], halfmin[rL * 4 + pb + 1]); \
            float thrm = vt + W; \
            uint blo = 0, bhi = 0; \
            _Pragma("unroll") for (int n = 0; n < 4; n++) \
            _Pragma("unroll") for (int r = 0; r < 4; r++) { \
                float d = fmaf(-2.f, acc[n][m][r], c2v[n][r]); \
                int bit = n * 16 + (l4 << 2) + r; \
                if (d < thrm) { if (bit < 32) blo |= 1u << bit; else bhi |= 1u << (bit - 32); } \
            } \
            blo |= __shfl_xor(blo, 16); bhi |= __shfl_xor(bhi, 16); \
            blo |= __shfl_xor(blo, 32); bhi |= __shfl_xor(bhi, 32); \
            if (l4 == 0) maskS[rL * 4 + wcn] = make_uint2(blo, bhi); \
        } \
        __syncthreads(); \
        { \
            int T = tid >> 8, rL = tid & 255; \
            float vt = fminf(halfmin[rL * 4 + T * 2], halfmin[rL * 4 + T * 2 + 1]); \
            uint2 lo = maskS[rL * 4 + T * 2], hi = maskS[rL * 4 + T * 2 + 1]; \
            size_t o = (size_t)(nt * 2 + T) * MM + (size_t)(mtx) * 256 + rL; \
            blockv1[o] = vt; \
            blockmask[o] = make_uint4(lo.x, lo.y, hi.x, hi.y); \
        } \
    } while (0)

    // prologue: stage virtual tile 0, drain, barrier
    STAGE4(aS0, 0, 0);
    WAIT0();
    BARX();

    for (int vt = 0; vt < 16; vt++) {
        const uint ab = (uint)(vt & 1) * 65536u;
        const int nbuf = (vt & 1) ^ 1;
        if (vt < 15) {
            int nv = vt + 1;
            STAGE4((nv < 8 ? aS0 : aS1), nv & 7, nbuf);
        }
        LDBALL();
        LDA(0);
        PH(0);
        LDA(1);
        PH(1);
        if (vt < 15) WAIT0();
        BARX();
        if (vt == 7) {
            EPI(mt0);                       // panel 0 masks out mid-kernel
            #pragma unroll
            for (int n = 0; n < 4; n++)
                #pragma unroll
                for (int m = 0; m < 8; m++) acc[n][m] = (f32x4){0.f, 0.f, 0.f, 0.f};
            __syncthreads();                // scratch reads done before vt8+ proceeds
        }
    }
    EPI(mt0 + 1);

    #undef STAGEQ
    #undef STAGE4
    #undef LDA
    #undef LDBALL
    #undef PH
    #undef EPI
}

// ---------------- combine + exact refine + update: ONE WAVE PER ROW, no barriers ----
// At q==QQ-1: writes quantized = x - new_resid directly (final fused).
__global__ __launch_bounds__(256) void crru_kernel(
    const float*  __restrict__ blockv1,
    const uint4*  __restrict__ blockmask,
    const float*  __restrict__ cbq,
    const float*  __restrict__ cb2q,
    const float*  __restrict__ xin,
    float*        __restrict__ resid,
    float*        __restrict__ idx_out,
    short8*       __restrict__ ah,
    int q, float W)
{
    __shared__ float rs[4][DD];          // 8 KB: per-wave resid row
    const int wid  = threadIdx.x >> 6;
    const int lane = threadIdx.x & 63;
    const int row  = blockIdx.x * 4 + wid;
    const int grp  = lane >> 4, gl = lane & 15;

    float v1 = 3.4e38f;
    uint4 mk = make_uint4(0, 0, 0, 0);
    if (lane < NTILES) {
        size_t o = (size_t)lane * MM + row;
        v1 = blockv1[o];
        mk = blockmask[o];
    }

    float* rrow = resid + (size_t)row * DD + lane * 8;
    float4 r0 = *(const float4*)rrow;
    float4 r1 = *(const float4*)(rrow + 4);
    *(float4*)&rs[wid][lane * 8]     = r0;
    *(float4*)&rs[wid][lane * 8 + 4] = r1;

    float g1 = v1;
    #pragma unroll
    for (int off = 32; off >= 1; off >>= 1) g1 = fminf(g1, __shfl_xor(g1, off));
    const float thr = g1 + W;

    unsigned long long act = __ballot((lane < NTILES) && (v1 < thr));

    float be = 3.4e38f; int bk = 0x7FFFFFFF;
    const float* rsw = rs[wid];

    auto eval4 = [&](int k0, int k1, int k2, int k3) {
        int kg = (grp == 0) ? k0 : (grp == 1) ? k1 : (grp == 2) ? k2 : k3;
        float d = 0.f;
        if (kg >= 0) {
            const float* cp = cbq + (size_t)kg * DD + gl * 32;
            const float* rp = rsw + gl * 32;
            #pragma unroll
            for (int j = 0; j < 8; j++) {
                float4 c = *(const float4*)(cp + j * 4);
                float4 r = *(const float4*)(rp + j * 4);
                d = fmaf(r.x, c.x, d); d = fmaf(r.y, c.y, d);
                d = fmaf(r.z, c.z, d); d = fmaf(r.w, c.w, d);
            }
        }
        #pragma unroll
        for (int off = 8; off >= 1; off >>= 1) d += __shfl_xor(d, off);
        #pragma unroll
        for (int g = 0; g < 4; g++) {
            float dg = __shfl(d, g * 16);
            int kg2 = (g == 0) ? k0 : (g == 1) ? k1 : (g == 2) ? k2 : k3;
            if (kg2 >= 0) {
                float e = fmaf(-2.f, dg, cb2q[kg2]);
                if (e < be || (e == be && kg2 < bk)) { be = e; bk = kg2; }
            }
        }
    };

    while (act) {
        int tile = __ffsll(act) - 1; act &= act - 1;
        uint m0 = __shfl((int)mk.x, tile), m1 = __shfl((int)mk.y, tile);
        uint m2 = __shfl((int)mk.z, tile), m3 = __shfl((int)mk.w, tile);
        unsigned long long lo = ((unsigned long long)m1 << 32) | m0;
        unsigned long long hi = ((unsigned long long)m3 << 32) | m2;
        int base = tile * 128;
        while (lo | hi) {
            int c0 = -1, c1 = -1, c2 = -1, c3 = -1;
            #define POP1(dst) \
                if (lo) { int b = __ffsll(lo) - 1; lo &= lo - 1; dst = base + b; } \
                else if (hi) { int b = __ffsll(hi) - 1; hi &= hi - 1; dst = base + 64 + b; }
            POP1(c0) POP1(c1) POP1(c2) POP1(c3)
            #undef POP1
            eval4(c0, c1, c2, c3);
        }
    }
    const int winner = bk;   // identical in all lanes

    if (lane == 0) {
        int b = row >> 11, l = row & (LL - 1);
        idx_out[((size_t)b * QQ + q) * LL + l] = (float)winner;
    }

    const float* cw = cbq + (size_t)winner * DD + lane * 8;
    float4 c0 = *(const float4*)cw;
    float4 c1 = *(const float4*)(cw + 4);
    float4 n0 = make_float4(r0.x - c0.x, r0.y - c0.y, r0.z - c0.z, r0.w - c0.w);
    float4 n1 = make_float4(r1.x - c1.x, r1.y - c1.y, r1.z - c1.z, r1.w - c1.w);

    if (q < QQ - 1) {
        *(float4*)rrow       = n0;
        *(float4*)(rrow + 4) = n1;
        short8 h;
        h[0] = (short)f2bf(n0.x); h[1] = (short)f2bf(n0.y);
        h[2] = (short)f2bf(n0.z); h[3] = (short)f2bf(n0.w);
        h[4] = (short)f2bf(n1.x); h[5] = (short)f2bf(n1.y);
        h[6] = (short)f2bf(n1.z); h[7] = (short)f2bf(n1.w);
        ah[(size_t)row * 64 + lane] = h;   // coalesced 1 KB/row
    } else {
        // final level: quantized = x - resid_final, written directly
        const float* xw = xin + (size_t)row * DD + lane * 8;
        float4 x0 = *(const float4*)xw;
        float4 x1 = *(const float4*)(xw + 4);
        *(float4*)rrow       = make_float4(x0.x - n0.x, x0.y - n0.y, x0.z - n0.z, x0.w - n0.w);
        *(float4*)(rrow + 4) = make_float4(x1.x - n1.x, x1.y - n1.y, x1.z - n1.z, x1.w - n1.w);
    }
}

extern "C" void kernel_launch(void* const* d_in, const int* in_sizes, int n_in,
                              void* d_out, int out_size, void* d_ws, size_t ws_size,
                              hipStream_t stream) {
    (void)in_sizes; (void)n_in; (void)out_size; (void)ws_size;
    const float* x  = (const float*)d_in[0];
    const float* cb = (const float*)d_in[1];
    float* out = (float*)d_out;

    float* idx_out = out;                           // BB*QQ*LL floats
    float* resid   = out + (size_t)BB * QQ * LL;    // doubles as quantized output

    char* w = (char*)d_ws;
    float*  cb2       = (float*)(w);                 // 64 KB
    float*  blockv1   = (float*)(w + 0x10000);       // 1 MB  -> ends 0x110000
    uint4*  blockmask = (uint4*)(w + 0x110000);      // 4 MB  -> ends 0x510000
    short8* ah        = (short8*)(w + 0x510000);     // 16 MB -> ends 0x1510000
    short8* bh2all    = (short8*)(w + 0x1510000);    // 16 MB -> ends 0x2510000 (~37 MB)

    cb2_kernel<<<QQ * KK / 4, 256, 0, stream>>>(cb, cb2);
    bprep_kernel<<<QQ * KK / 4, 256, 0, stream>>>(cb, bh2all);     // all levels, once
    aprep0_kernel<<<MM / 4, 256, 0, stream>>>(x, resid, ah);

    for (int q = 0; q < QQ; q++) {
        const float* cbq  = cb + (size_t)q * KK * DD;
        const float* c2q  = cb2 + (size_t)q * KK;
        const short8* bhq = bh2all + (size_t)q * KK * 64;
        const float W = 2.0f + 0.3f * q;   // proven coverage window (R7-R9)

        gemm_argmin_kernel<<<256, 512, 0, stream>>>(ah, bhq, c2q,
                                                    blockv1, blockmask, W);

        crru_kernel<<<MM / 4, 256, 0, stream>>>(blockv1, blockmask, cbq, c2q, x,
                                                resid, idx_out, ah, q, W);
    }
}

// Round 11
// 501.006 us; speedup vs baseline: 4.2317x; 1.2946x over previous
//
#include <hip/hip_runtime.h>

#define BB 8
#define LL 2048
#define DD 512
#define QQ 8
#define KK 2048
#define MM (BB*LL)      // 16384 points

#define NTILES 16       // 16 col-tiles of 128

typedef __attribute__((ext_vector_type(8))) short short8;
typedef __attribute__((ext_vector_type(4))) float f32x4;

#define GLDS(src, dst) __builtin_amdgcn_global_load_lds( \
    (const __attribute__((address_space(1))) void*)(src), \
    (__attribute__((address_space(3))) void*)(dst), 16, 0, 0)

#define BARX()  asm volatile("s_barrier" ::: "memory")
#define WAIT0() asm volatile("s_waitcnt vmcnt(0)" ::: "memory")

__device__ __forceinline__ ushort f2bf(float f) {
    uint u = __float_as_uint(f);
    u += 0x7FFFu + ((u >> 16) & 1u);
    return (ushort)(u >> 16);
}

// ---------------- B prep ALL LEVELS once + fused squared norms ----------------
// bh2all[(q*KK+col)*64 + j] = bf16 of cb[q][col][j*8..j*8+8);  cb2[q*KK+col] = ||c||^2
// Codebooks are input-static -> off the per-level critical path (9 dispatches removed).
__global__ __launch_bounds__(256) void bprep_kernel(const float* __restrict__ cb,
                                                    short8* __restrict__ bh2all,
                                                    float* __restrict__ cb2) {
    const int wid  = threadIdx.x >> 6;
    const int lane = threadIdx.x & 63;
    const int col  = blockIdx.x * 4 + wid;      // 0 .. QQ*KK-1
    const float* src = cb + (size_t)col * DD + lane * 8;
    float4 v0 = *(const float4*)src;
    float4 v1 = *(const float4*)(src + 4);
    short8 h;
    h[0] = (short)f2bf(v0.x); h[1] = (short)f2bf(v0.y);
    h[2] = (short)f2bf(v0.z); h[3] = (short)f2bf(v0.w);
    h[4] = (short)f2bf(v1.x); h[5] = (short)f2bf(v1.y);
    h[6] = (short)f2bf(v1.z); h[7] = (short)f2bf(v1.w);
    bh2all[(size_t)col * 64 + lane] = h;
    float s = v0.x*v0.x + v0.y*v0.y + v0.z*v0.z + v0.w*v0.w
            + v1.x*v1.x + v1.y*v1.y + v1.z*v1.z + v1.w*v1.w;
    #pragma unroll
    for (int off = 32; off >= 1; off >>= 1) s += __shfl_xor(s, off);
    if (lane == 0) cb2[col] = s;
}

// ---------------- level-0 A prep: resid <- x, ah <- bf16(x) [row][lane] ----------------
__global__ __launch_bounds__(256) void aprep0_kernel(const float* __restrict__ x,
                                                     float* __restrict__ resid,
                                                     short8* __restrict__ ah) {
    const int wid  = threadIdx.x >> 6;
    const int lane = threadIdx.x & 63;
    const int row  = blockIdx.x * 4 + wid;
    const float* src = x + (size_t)row * DD + lane * 8;
    float4 v0 = *(const float4*)src;
    float4 v1 = *(const float4*)(src + 4);
    float* dst = resid + (size_t)row * DD + lane * 8;
    *(float4*)dst       = v0;
    *(float4*)(dst + 4) = v1;
    short8 h;
    h[0] = (short)f2bf(v0.x); h[1] = (short)f2bf(v0.y);
    h[2] = (short)f2bf(v0.z); h[3] = (short)f2bf(v0.w);
    h[4] = (short)f2bf(v1.x); h[5] = (short)f2bf(v1.y);
    h[6] = (short)f2bf(v1.z); h[7] = (short)f2bf(v1.w);
    ah[(size_t)row * 64 + lane] = h;
}

// ---------------- 256x256 BK=64 bf16 GEMM + per-tile (v1, mask) — r8-proven ----------------
// 512 blocks x 512 thr (8 waves 2Mx4N, wave tile 128x64), 8 K-tiles, ONE panel per
// block (per-XCD L2 working set ~2.2MB, resident; two-panel variant thrashed L2).
// 1 barrier-pair per K-tile, compiler-scheduled body, XOR-swizzled GLDS staging.
__global__ __launch_bounds__(512, 2) void gemm_argmin_kernel(
    const short8* __restrict__ ah,
    const short8* __restrict__ bh2q,
    const float*  __restrict__ cb2q,
    float*        __restrict__ blockv1,    // [NTILES][MM]
    uint4*        __restrict__ blockmask,  // [NTILES][MM]
    float W)
{
    __shared__ char smemc[131072];   // [2 buf][A 32KB | B 32KB]

    const int id  = blockIdx.x;
    const int xcd = id & 7;
    const int s   = id >> 3;             // 0..63
    const int nt  = s & 7;               // 0..7 (256-col tiles)
    const int mt  = xcd * 8 + (s >> 3);  // 0..63 (256-row tiles), A reuse per XCD

    const int tid  = threadIdx.x;
    const int wid  = tid >> 6;
    const int lane = tid & 63;
    const int wr   = wid >> 2;           // rows [wr*128, +128)
    const int wcn  = wid & 3;            // cols [wcn*64, +64)
    const int l15  = lane & 15, l4 = lane >> 4;

    f32x4 acc[4][8];
    #pragma unroll
    for (int n = 0; n < 4; n++)
        #pragma unroll
        for (int m = 0; m < 8; m++) acc[n][m] = (f32x4){0.f, 0.f, 0.f, 0.f};

    const char* aSrc = (const char*)ah   + ((size_t)mt << 18);   // 256 rows x 1 KB
    const char* bSrc = (const char*)bh2q + ((size_t)nt << 18);

    #define STAGEQ(tt, bufn, p) do { \
        int g_ = (p) * 512 + tid; \
        int rL_ = g_ >> 3, st_ = g_ & 7; \
        int k_ = st_ ^ (rL_ & 7); \
        char* db_ = smemc + (bufn) * 65536 + ((p) * 512 + wid * 64) * 16; \
        GLDS(aSrc + (size_t)rL_ * 1024 + (tt) * 128 + k_ * 16, db_); \
        GLDS(bSrc + (size_t)rL_ * 1024 + (tt) * 128 + k_ * 16, db_ + 32768); \
    } while (0)

    short8 af[4][2], bf[4][2];

    #define LDA(mh) do { \
        _Pragma("unroll") for (int mm = 0; mm < 4; mm++) \
        _Pragma("unroll") for (int ks = 0; ks < 2; ks++) { \
            int rL_ = wr * 128 + ((mh) * 4 + mm) * 16 + l15; \
            int c_ = ks * 4 + l4; \
            af[mm][ks] = *(const short8*)(smemc + ab + rL_ * 128 + ((c_ ^ (rL_ & 7)) << 4)); \
        } } while (0)

    #define LDBALL() do { \
        _Pragma("unroll") for (int nn = 0; nn < 4; nn++) \
        _Pragma("unroll") for (int ks = 0; ks < 2; ks++) { \
            int cL_ = wcn * 64 + nn * 16 + l15; \
            int c_ = ks * 4 + l4; \
            bf[nn][ks] = *(const short8*)(smemc + ab + 32768 + cL_ * 128 + ((c_ ^ (cL_ & 7)) << 4)); \
        } } while (0)

    #define PH(mh) do { \
        __builtin_amdgcn_s_setprio(1); \
        _Pragma("unroll") for (int ks = 0; ks < 2; ks++) \
        _Pragma("unroll") for (int nn = 0; nn < 4; nn++) \
        _Pragma("unroll") for (int mm = 0; mm < 4; mm++) \
            acc[nn][(mh)*4+mm] = __builtin_amdgcn_mfma_f32_16x16x32_bf16( \
                bf[nn][ks], af[mm][ks], acc[nn][(mh)*4+mm], 0, 0, 0); \
        __builtin_amdgcn_s_setprio(0); \
    } while (0)

    STAGEQ(0, 0, 0); STAGEQ(0, 0, 1); STAGEQ(0, 0, 2); STAGEQ(0, 0, 3);
    WAIT0();
    BARX();

    for (int t = 0; t < 8; t++) {
        const uint ab = (uint)(t & 1) * 65536u;
        const int nbuf = (t & 1) ^ 1;
        if (t < 7) { STAGEQ(t + 1, nbuf, 0); STAGEQ(t + 1, nbuf, 1);
                     STAGEQ(t + 1, nbuf, 2); STAGEQ(t + 1, nbuf, 3); }
        LDBALL();
        LDA(0);
        PH(0);
        LDA(1);
        PH(1);
        if (t < 7) WAIT0();
        BARX();
    }

    // ---- mask epilogue (r8-verbatim) ----
    float* halfmin = (float*)smemc;             // [256][4 wcn]  4 KB
    uint2* maskS   = (uint2*)(smemc + 4096);    // [256][4 wcn]  8 KB

    f32x4 c2v[4];
    #pragma unroll
    for (int n = 0; n < 4; n++)
        c2v[n] = *(const f32x4*)&cb2q[nt * 256 + wcn * 64 + n * 16 + (l4 << 2)];

    #pragma unroll
    for (int m = 0; m < 8; m++) {
        float v = 3.4e38f;
        #pragma unroll
        for (int n = 0; n < 4; n++)
            #pragma unroll
            for (int r = 0; r < 4; r++)
                v = fminf(v, fmaf(-2.f, acc[n][m][r], c2v[n][r]));
        v = fminf(v, __shfl_xor(v, 16));
        v = fminf(v, __shfl_xor(v, 32));
        if (l4 == 0) halfmin[(wr * 128 + m * 16 + l15) * 4 + wcn] = v;
    }
    __syncthreads();

    #pragma unroll
    for (int m = 0; m < 8; m++) {
        int rL = wr * 128 + m * 16 + l15;
        int pb = wcn & 2;
        float vt = fminf(halfmin[rL * 4 + pb], halfmin[rL * 4 + pb + 1]);
        float thrm = vt + W;
        uint blo = 0, bhi = 0;
        #pragma unroll
        for (int n = 0; n < 4; n++)
            #pragma unroll
            for (int r = 0; r < 4; r++) {
                float d = fmaf(-2.f, acc[n][m][r], c2v[n][r]);
                int bit = n * 16 + (l4 << 2) + r;
                if (d < thrm) { if (bit < 32) blo |= 1u << bit; else bhi |= 1u << (bit - 32); }
            }
        blo |= __shfl_xor(blo, 16); bhi |= __shfl_xor(bhi, 16);
        blo |= __shfl_xor(blo, 32); bhi |= __shfl_xor(bhi, 32);
        if (l4 == 0) maskS[rL * 4 + wcn] = make_uint2(blo, bhi);
    }
    __syncthreads();

    {
        int T = tid >> 8, rL = tid & 255;
        float vt = fminf(halfmin[rL * 4 + T * 2], halfmin[rL * 4 + T * 2 + 1]);
        uint2 lo = maskS[rL * 4 + T * 2], hi = maskS[rL * 4 + T * 2 + 1];
        size_t o = (size_t)(nt * 2 + T) * MM + mt * 256 + rL;
        blockv1[o] = vt;
        blockmask[o] = make_uint4(lo.x, lo.y, hi.x, hi.y);
    }
    #undef STAGEQ
    #undef LDA
    #undef LDBALL
    #undef PH
}

// ---------------- combine + exact refine + update: ONE WAVE PER ROW, no barriers ----
// At q==QQ-1: writes quantized = x - new_resid directly (final fused).
__global__ __launch_bounds__(256) void crru_kernel(
    const float*  __restrict__ blockv1,
    const uint4*  __restrict__ blockmask,
    const float*  __restrict__ cbq,
    const float*  __restrict__ cb2q,
    const float*  __restrict__ xin,
    float*        __restrict__ resid,
    float*        __restrict__ idx_out,
    short8*       __restrict__ ah,
    int q, float W)
{
    __shared__ float rs[4][DD];          // 8 KB: per-wave resid row
    const int wid  = threadIdx.x >> 6;
    const int lane = threadIdx.x & 63;
    const int row  = blockIdx.x * 4 + wid;
    const int grp  = lane >> 4, gl = lane & 15;

    float v1 = 3.4e38f;
    uint4 mk = make_uint4(0, 0, 0, 0);
    if (lane < NTILES) {
        size_t o = (size_t)lane * MM + row;
        v1 = blockv1[o];
        mk = blockmask[o];
    }

    float* rrow = resid + (size_t)row * DD + lane * 8;
    float4 r0 = *(const float4*)rrow;
    float4 r1 = *(const float4*)(rrow + 4);
    *(float4*)&rs[wid][lane * 8]     = r0;
    *(float4*)&rs[wid][lane * 8 + 4] = r1;

    float g1 = v1;
    #pragma unroll
    for (int off = 32; off >= 1; off >>= 1) g1 = fminf(g1, __shfl_xor(g1, off));
    const float thr = g1 + W;

    unsigned long long act = __ballot((lane < NTILES) && (v1 < thr));

    float be = 3.4e38f; int bk = 0x7FFFFFFF;
    const float* rsw = rs[wid];

    auto eval4 = [&](int k0, int k1, int k2, int k3) {
        int kg = (grp == 0) ? k0 : (grp == 1) ? k1 : (grp == 2) ? k2 : k3;
        float d = 0.f;
        if (kg >= 0) {
            const float* cp = cbq + (size_t)kg * DD + gl * 32;
            const float* rp = rsw + gl * 32;
            #pragma unroll
            for (int j = 0; j < 8; j++) {
                float4 c = *(const float4*)(cp + j * 4);
                float4 r = *(const float4*)(rp + j * 4);
                d = fmaf(r.x, c.x, d); d = fmaf(r.y, c.y, d);
                d = fmaf(r.z, c.z, d); d = fmaf(r.w, c.w, d);
            }
        }
        #pragma unroll
        for (int off = 8; off >= 1; off >>= 1) d += __shfl_xor(d, off);
        #pragma unroll
        for (int g = 0; g < 4; g++) {
            float dg = __shfl(d, g * 16);
            int kg2 = (g == 0) ? k0 : (g == 1) ? k1 : (g == 2) ? k2 : k3;
            if (kg2 >= 0) {
                float e = fmaf(-2.f, dg, cb2q[kg2]);
                if (e < be || (e == be && kg2 < bk)) { be = e; bk = kg2; }
            }
        }
    };

    while (act) {
        int tile = __ffsll(act) - 1; act &= act - 1;
        uint m0 = __shfl((int)mk.x, tile), m1 = __shfl((int)mk.y, tile);
        uint m2 = __shfl((int)mk.z, tile), m3 = __shfl((int)mk.w, tile);
        unsigned long long lo = ((unsigned long long)m1 << 32) | m0;
        unsigned long long hi = ((unsigned long long)m3 << 32) | m2;
        int base = tile * 128;
        while (lo | hi) {
            int c0 = -1, c1 = -1, c2 = -1, c3 = -1;
            #define POP1(dst) \
                if (lo) { int b = __ffsll(lo) - 1; lo &= lo - 1; dst = base + b; } \
                else if (hi) { int b = __ffsll(hi) - 1; hi &= hi - 1; dst = base + 64 + b; }
            POP1(c0) POP1(c1) POP1(c2) POP1(c3)
            #undef POP1
            eval4(c0, c1, c2, c3);
        }
    }
    const int winner = bk;   // identical in all lanes

    if (lane == 0) {
        int b = row >> 11, l = row & (LL - 1);
        idx_out[((size_t)b * QQ + q) * LL + l] = (float)winner;
    }

    const float* cw = cbq + (size_t)winner * DD + lane * 8;
    float4 c0 = *(const float4*)cw;
    float4 c1 = *(const float4*)(cw + 4);
    float4 n0 = make_float4(r0.x - c0.x, r0.y - c0.y, r0.z - c0.z, r0.w - c0.w);
    float4 n1 = make_float4(r1.x - c1.x, r1.y - c1.y, r1.z - c1.z, r1.w - c1.w);

    if (q < QQ - 1) {
        *(float4*)rrow       = n0;
        *(float4*)(rrow + 4) = n1;
        short8 h;
        h[0] = (short)f2bf(n0.x); h[1] = (short)f2bf(n0.y);
        h[2] = (short)f2bf(n0.z); h[3] = (short)f2bf(n0.w);
        h[4] = (short)f2bf(n1.x); h[5] = (short)f2bf(n1.y);
        h[6] = (short)f2bf(n1.z); h[7] = (short)f2bf(n1.w);
        ah[(size_t)row * 64 + lane] = h;   // coalesced 1 KB/row
    } else {
        // final level: quantized = x - resid_final, written directly
        const float* xw = xin + (size_t)row * DD + lane * 8;
        float4 x0 = *(const float4*)xw;
        float4 x1 = *(const float4*)(xw + 4);
        *(float4*)rrow       = make_float4(x0.x - n0.x, x0.y - n0.y, x0.z - n0.z, x0.w - n0.w);
        *(float4*)(rrow + 4) = make_float4(x1.x - n1.x, x1.y - n1.y, x1.z - n1.z, x1.w - n1.w);
    }
}

extern "C" void kernel_launch(void* const* d_in, const int* in_sizes, int n_in,
                              void* d_out, int out_size, void* d_ws, size_t ws_size,
                              hipStream_t stream) {
    (void)in_sizes; (void)n_in; (void)out_size; (void)ws_size;
    const float* x  = (const float*)d_in[0];
    const float* cb = (const float*)d_in[1];
    float* out = (float*)d_out;

    float* idx_out = out;                           // BB*QQ*LL floats
    float* resid   = out + (size_t)BB * QQ * LL;    // doubles as quantized output

    char* w = (char*)d_ws;
    float*  cb2       = (float*)(w);                 // 64 KB
    float*  blockv1   = (float*)(w + 0x10000);       // 1 MB  -> ends 0x110000
    uint4*  blockmask = (uint4*)(w + 0x110000);      // 4 MB  -> ends 0x510000
    short8* ah        = (short8*)(w + 0x510000);     // 16 MB -> ends 0x1510000
    short8* bh2all    = (short8*)(w + 0x1510000);    // 16 MB -> ends 0x2510000 (~37 MB)

    bprep_kernel<<<QQ * KK / 4, 256, 0, stream>>>(cb, bh2all, cb2);  // all levels + norms, once
    aprep0_kernel<<<MM / 4, 256, 0, stream>>>(x, resid, ah);

    for (int q = 0; q < QQ; q++) {
        const float* cbq  = cb + (size_t)q * KK * DD;
        const float* c2q  = cb2 + (size_t)q * KK;
        const short8* bhq = bh2all + (size_t)q * KK * 64;
        const float W = 2.0f + 0.3f * q;   // proven coverage window (R7-R9)

        gemm_argmin_kernel<<<512, 512, 0, stream>>>(ah, bhq, c2q,
                                                    blockv1, blockmask, W);

        crru_kernel<<<MM / 4, 256, 0, stream>>>(blockv1, blockmask, cbq, c2q, x,
                                                resid, idx_out, ah, q, W);
    }
}